// Round 5
// baseline (170.447 us; speedup 1.0000x reference)
//
#include <hip/hip_runtime.h>

#define IN_F 512
#define OUT_F 1024
#define K_ACTIVE 11  // ceil(0.01 * 1024) serial MP steps
#define K_IN 6       // ceil(0.01 * 512) kwta winners

// 32x32 LDS-tiled transpose: w [OUT_F][IN_F] -> wT [IN_F][OUT_F]
__global__ __launch_bounds__(256) void transpose_w_kernel(const float* __restrict__ w,
                                                          float* __restrict__ wT) {
    __shared__ float tile[32][33];
    const int tx = threadIdx.x & 31;
    const int ty = threadIdx.x >> 5;  // 0..7
    const int i0 = blockIdx.x * 32;   // IN_F tile base
    const int j0 = blockIdx.y * 32;   // OUT_F tile base
#pragma unroll
    for (int k = 0; k < 4; ++k)
        tile[ty + 8 * k][tx] = w[(size_t)(j0 + ty + 8 * k) * IN_F + (i0 + tx)];
    __syncthreads();
#pragma unroll
    for (int k = 0; k < 4; ++k)
        wT[(size_t)(i0 + ty + 8 * k) * OUT_F + (j0 + tx)] = tile[tx][ty + 8 * k];
}

// ---- order-preserving fp64 -> u64 key, low bits carry reversed index ----
// max(key) == max value; ties -> lowest index. Drops 10 mantissa bits (2^-42 rel).
__device__ __forceinline__ unsigned long long pack_key(double v, unsigned rev,
                                                       unsigned long long mask) {
    unsigned long long b = (unsigned long long)__double_as_longlong(v);
    unsigned long long m =
        (unsigned long long)((long long)b >> 63) | 0x8000000000000000ull;
    unsigned long long u = b ^ m;  // monotonic total order
    return (u & ~mask) | (unsigned long long)rev;
}

// ---- wave-wide u64 max via DPP (VALU-speed, no LDS): result uniform ----
template <int C>
__device__ __forceinline__ unsigned long long dppmax(unsigned long long k) {
    unsigned lo = (unsigned)__builtin_amdgcn_update_dpp(0, (int)(unsigned)k, C, 0xF, 0xF, true);
    unsigned hi = (unsigned)__builtin_amdgcn_update_dpp(0, (int)(unsigned)(k >> 32), C, 0xF, 0xF, true);
    unsigned long long o = ((unsigned long long)hi << 32) | lo;
    return o > k ? o : k;
}

__device__ __forceinline__ unsigned long long wave_max_u64(unsigned long long k) {
    k = dppmax<0x111>(k);  // row_shr:1
    k = dppmax<0x112>(k);  // row_shr:2
    k = dppmax<0x114>(k);  // row_shr:4
    k = dppmax<0x118>(k);  // row_shr:8
    k = dppmax<0x142>(k);  // row_bcast:15
    k = dppmax<0x143>(k);  // row_bcast:31  -> lane 63 has wave max
    unsigned glo = (unsigned)__builtin_amdgcn_readlane((int)(unsigned)k, 63);
    unsigned ghi = (unsigned)__builtin_amdgcn_readlane((int)(unsigned)(k >> 32), 63);
    return ((unsigned long long)ghi << 32) | glo;
}

// Half-row axpy: r[s] += sgn * wT[i][j(s)], j = wv*512 + c*256 + lane*4 + e, s=4c+e.
// USE_T: 2 float4 loads, each 64 lanes x 16B = 1KB contiguous (coalesced).
template <bool USE_T>
__device__ __forceinline__ void wt_row_axpy(double* r, const float* __restrict__ wT,
                                            const float* __restrict__ w, int i,
                                            double sgn, int lane, int wv) {
    if constexpr (USE_T) {
        const float* rp = wT + ((size_t)i << 10) + (wv << 9) + (lane << 2);
#pragma unroll
        for (int c = 0; c < 2; ++c) {
            const float4 f = *(const float4*)(rp + (c << 8));
            r[4 * c + 0] += sgn * (double)f.x;
            r[4 * c + 1] += sgn * (double)f.y;
            r[4 * c + 2] += sgn * (double)f.z;
            r[4 * c + 3] += sgn * (double)f.w;
        }
    } else {
#pragma unroll
        for (int s = 0; s < 8; ++s) {
            int j = (wv << 9) | ((s >> 2) << 8) | (lane << 2) | (s & 3);
            r[s] += sgn * (double)w[(size_t)j * IN_F + i];
        }
    }
}

// 2 waves per row: wave wv owns OUT j in [wv*512, wv*512+512) (r[8] = 16 VGPR)
// and IN i in [wv*256, wv*256+256) (vd[4] = 8 VGPR). Persistent fp64 state ~30
// VGPR -> fits the allocator's 64-VGPR/8-waves-per-EU target with NO scratch
// (R3/R4: 1-wave layout spilled 50-120 MB to scratch at VGPR_Count=64).
template <bool USE_T>
__global__ __launch_bounds__(128) void bmp_kernel(const float* __restrict__ x,
                                                  const float* __restrict__ w,
                                                  const float* __restrict__ wT,
                                                  float* __restrict__ out, int rows) {
    __shared__ unsigned short act[IN_F + 8];
    __shared__ unsigned long long kx[4];  // parity-double-buffered reduction slots
    const int lane = threadIdx.x & 63;
    const int wv = threadIdx.x >> 6;
    const int row = blockIdx.x;
    if (row >= rows) return;

    // ---- compacted active list of x row (both waves compute identical ballots;
    //      wave 0 writes) ----
    const float* xrow = x + (size_t)row * IN_F;
    int cnt = 0;
#pragma unroll
    for (int c = 0; c < IN_F / 64; ++c) {
        bool pbit = xrow[c * 64 + lane] != 0.0f;
        unsigned long long m = __ballot(pbit);
        int pre = __popcll(m & ((1ull << lane) - 1ull));
        if (wv == 0 && pbit) act[cnt + pre] = (unsigned short)(c * 64 + lane);
        cnt += __popcll(m);
    }
    __syncthreads();

    int rc = 0;  // reduction counter (identical in all threads)
    auto block_max = [&](unsigned long long k) -> unsigned long long {
        const unsigned long long wm = wave_max_u64(k);  // uniform within wave
        if (lane == 0) kx[((rc & 1) << 1) | wv] = wm;
        __syncthreads();
        const unsigned long long a = kx[(rc & 1) << 1];
        const unsigned long long b = kx[((rc & 1) << 1) | 1];
        ++rc;
        return a > b ? a : b;
    };

    // ---- r = 2 * x @ wT (half-row per wave, fp64; maintained incrementally) ----
    double r[8];
#pragma unroll
    for (int s = 0; s < 8; ++s) r[s] = 0.0;
    {
        int iu = act[0];
#pragma unroll 1
        for (int k = 0; k < cnt; ++k) {
            int inx = act[k + 1];  // prefetch next (act oversized; tail value unused)
            wt_row_axpy<USE_T>(r, wT, w, iu, 1.0, lane, wv);
            iu = inx;
        }
    }
#pragma unroll
    for (int s = 0; s < 8; ++s) r[s] *= 2.0;

    double vd[4];  // quarter of v = encoded @ W: i = wv*256 + lane*4 + p
#pragma unroll
    for (int p = 0; p < 4; ++p) vd[p] = 0.0;

    unsigned enc = 0;      // per-lane 8-bit slot mask over this wave's OUT slots
    unsigned selmask = 0;  // per-lane 4-bit mask of final xr slots
    int O0 = -1, O1 = -1, O2 = -1, O3 = -1, O4 = -1, O5 = -1;  // xr set (uniform)

#pragma unroll 1
    for (int t = 0; t < K_ACTIVE; ++t) {
        // ---- argmax of residual over non-encoded j (lambd >> |dot| => exclusion) ----
        unsigned long long kb = 0;
#pragma unroll
        for (int s = 0; s < 8; ++s) {
            int j = (wv << 9) | ((s >> 2) << 8) | (lane << 2) | (s & 3);
            unsigned long long key = pack_key(r[s], 1023u ^ (unsigned)j, 1023ull);
            key = (enc & (1u << s)) ? 0ull : key;
            kb = key > kb ? key : kb;
        }
        const unsigned long long g = block_max(kb);
        const int bestj =
            __builtin_amdgcn_readfirstlane(1023 ^ (int)(g & 1023ull));  // uniform
        if ((bestj >> 9) == wv && ((bestj >> 2) & 63) == lane)
            enc |= 1u << ((((bestj >> 8) & 1) << 2) | (bestj & 3));

        // ---- v += W[bestj][:] (one 1KB-contiguous float4 load per wave) ----
        {
            const float* wr = w + ((size_t)bestj << 9) + (wv << 8) + (lane << 2);
            const float4 f = *(const float4*)wr;
            vd[0] += (double)f.x;
            vd[1] += (double)f.y;
            vd[2] += (double)f.z;
            vd[3] += (double)f.w;
        }

        // ---- kwta: top-6 of v via 6 packed-key block max-reductions ----
        int N[6];
        {
            unsigned long long vkey[4];  // transient
#pragma unroll
            for (int p = 0; p < 4; ++p) {
                int i = (wv << 8) | (lane << 2) | p;
                vkey[p] = pack_key(vd[p], 511u ^ (unsigned)i, 511ull);
            }
#pragma unroll
            for (int s2 = 0; s2 < K_IN; ++s2) {
                unsigned long long lk = vkey[0];
#pragma unroll
                for (int p = 1; p < 4; ++p) lk = vkey[p] > lk ? vkey[p] : lk;
                const unsigned long long gk = block_max(lk);
                N[s2] = __builtin_amdgcn_readfirstlane(511 ^ (int)(gk & 511ull));
#pragma unroll
                for (int p = 0; p < 4; ++p) vkey[p] = (vkey[p] == gk) ? 0ull : vkey[p];
            }
            if (t == K_ACTIVE - 1) {
                selmask = 0;
#pragma unroll
                for (int p = 0; p < 4; ++p) selmask |= (vkey[p] == 0ull) ? (1u << p) : 0u;
            }
        }

        // ---- incremental residual update: set-diff of xr (uniform logic) ----
        if (t == 0) {
#pragma unroll
            for (int b = 0; b < 6; ++b) wt_row_axpy<USE_T>(r, wT, w, N[b], -1.0, lane, wv);
        } else if (t < K_ACTIVE - 1) {
#pragma unroll
            for (int a = 0; a < 6; ++a) {
                const int o = (a == 0) ? O0 : (a == 1) ? O1 : (a == 2) ? O2
                              : (a == 3) ? O3 : (a == 4) ? O4 : O5;
                const bool stay = (o == N[0]) | (o == N[1]) | (o == N[2]) |
                                  (o == N[3]) | (o == N[4]) | (o == N[5]);
                if (!stay) wt_row_axpy<USE_T>(r, wT, w, o, 1.0, lane, wv);
            }
#pragma unroll
            for (int b = 0; b < 6; ++b) {
                const int n = N[b];
                const bool was = (n == O0) | (n == O1) | (n == O2) |
                                 (n == O3) | (n == O4) | (n == O5);
                if (!was) wt_row_axpy<USE_T>(r, wT, w, n, -1.0, lane, wv);
            }
        }
        O0 = N[0]; O1 = N[1]; O2 = N[2]; O3 = N[3]; O4 = N[4]; O5 = N[5];
    }

    // ---- outputs: encoded [rows][OUT_F] then xr [rows][IN_F], coalesced float4 ----
    float* oe = out + (size_t)row * OUT_F + (wv << 9) + (lane << 2);
#pragma unroll
    for (int c = 0; c < 2; ++c) {
        float4 v;
        v.x = (enc & (1u << (4 * c + 0))) ? 1.0f : 0.0f;
        v.y = (enc & (1u << (4 * c + 1))) ? 1.0f : 0.0f;
        v.z = (enc & (1u << (4 * c + 2))) ? 1.0f : 0.0f;
        v.w = (enc & (1u << (4 * c + 3))) ? 1.0f : 0.0f;
        *(float4*)(oe + (c << 8)) = v;
    }
    float* ox = out + (size_t)rows * OUT_F + (size_t)row * IN_F + (wv << 8) + (lane << 2);
    {
        float4 v;
        v.x = (selmask & 1u) ? 1.0f : 0.0f;
        v.y = (selmask & 2u) ? 1.0f : 0.0f;
        v.z = (selmask & 4u) ? 1.0f : 0.0f;
        v.w = (selmask & 8u) ? 1.0f : 0.0f;
        *(float4*)ox = v;
    }
}

extern "C" void kernel_launch(void* const* d_in, const int* in_sizes, int n_in,
                              void* d_out, int out_size, void* d_ws, size_t ws_size,
                              hipStream_t stream) {
    const float* x = (const float*)d_in[0];
    const float* w = (const float*)d_in[1];
    float* out = (float*)d_out;
    const int rows = in_sizes[0] / IN_F;  // 4096

    const size_t wt_bytes = (size_t)IN_F * OUT_F * sizeof(float);
    if (ws_size >= wt_bytes && d_ws != nullptr) {
        float* wT = (float*)d_ws;
        transpose_w_kernel<<<dim3(IN_F / 32, OUT_F / 32), 256, 0, stream>>>(w, wT);
        bmp_kernel<true><<<rows, 128, 0, stream>>>(x, w, wT, out, rows);
    } else {
        bmp_kernel<false><<<rows, 128, 0, stream>>>(x, w, nullptr, out, rows);
    }
}